// Round 1
// baseline (276.953 us; speedup 1.0000x reference)
//
#include <hip/hip_runtime.h>
#include <cstdint>
#include <cstddef>

typedef __attribute__((ext_vector_type(8))) __bf16 bf16x8;
typedef __attribute__((ext_vector_type(4))) float f32x4;
typedef __attribute__((ext_vector_type(4))) unsigned short u16x4;
typedef __attribute__((ext_vector_type(8))) unsigned short u16x8;

static constexpr int Bz = 2, Sz = 2048, Gz = 4, Cz = 2048;
static constexpr int Hh = 16, EDz = 1024;
static constexpr int Tz = Bz * Sz;          // 4096 tokens
static constexpr int NALL = Gz * Cz + Cz;   // 10240 output cols (4 key branches + value)

__constant__ int OFF16[16] = {0, 100003, 200022, 300065, 400114, 500171, 600240,
                              700343, 800452, 900581, 1000732, 1100885, 1201054,
                              1301237, 1401426, 1501619};

__device__ __forceinline__ float bf2f(unsigned short s) {
  union { unsigned u; float f; } x; x.u = ((unsigned)s) << 16; return x.f;
}
__device__ __forceinline__ unsigned short f2bf(float f) {
  union { float f; unsigned u; } x; x.f = f;
  unsigned r = x.u + 0x7fff + ((x.u >> 16) & 1);
  return (unsigned short)(r >> 16);
}

// ---------------- bias concat: bias_all[10240] ----------------
__global__ __launch_bounds__(256) void k_bias(const float* __restrict__ key_b,
                                              const float* __restrict__ value_b,
                                              float* __restrict__ bias) {
  int n = blockIdx.x * 256 + threadIdx.x;
  bias[n] = (n < Gz * Cz) ? key_b[n] : value_b[n - Gz * Cz];
}

// ---------------- weight transpose + cast: Wt[n][k] bf16 ----------------
__global__ __launch_bounds__(256) void k_prepw(const float* __restrict__ key_w,
                                               const float* __restrict__ value_w,
                                               unsigned short* __restrict__ Wt) {
  __shared__ float tile[32][33];
  const int mat = blockIdx.y;                 // 0..3 key_w[g], 4 = value_w
  const int ot = blockIdx.x & 63, kt = blockIdx.x >> 6;
  const float* src = (mat < 4) ? (key_w + (size_t)mat * EDz * Cz) : value_w;
  const int tx = threadIdx.x & 31, ty = threadIdx.x >> 5;
#pragma unroll
  for (int i = 0; i < 4; i++)
    tile[ty + i * 8][tx] = src[(size_t)(kt * 32 + ty + i * 8) * Cz + ot * 32 + tx];
  __syncthreads();
#pragma unroll
  for (int i = 0; i < 4; i++)
    Wt[(size_t)(mat * Cz + ot * 32 + ty + i * 8) * EDz + kt * 32 + tx] =
        f2bf(tile[tx][ty + i * 8]);
}

// ---------------- gather + cast: emb[t][1024] bf16 ----------------
__global__ __launch_bounds__(256) void k_gather(const int* __restrict__ ids,
                                                const float* __restrict__ table,
                                                unsigned short* __restrict__ emb) {
  const int t = blockIdx.x;
  const int tid = threadIdx.x;
  const int h = tid >> 4;
  const int d = (tid & 15) * 4;
  const long row = (long)(ids[t * Hh + h] + OFF16[h]);
  f32x4 v = *reinterpret_cast<const f32x4*>(table + row * 64 + d);
  u16x4 o;
#pragma unroll
  for (int i = 0; i < 4; i++) o[i] = f2bf(v[i]);
  *reinterpret_cast<u16x4*>(emb + (size_t)t * EDz + tid * 4) = o;
}

// ---------------- GEMM: kv[4096][10240] = emb @ Wt^T + bias (bf16 out) ----------------
// m97 structure: 128x128 tile, BK=32, 4 waves (2x2 of 64x64), 16x16x32 MFMA
__global__ __launch_bounds__(256) void k_gemm(const unsigned short* __restrict__ A,
                                              const unsigned short* __restrict__ Bw,
                                              const float* __restrict__ bias,
                                              unsigned short* __restrict__ Cm) {
  __shared__ unsigned short As[128 * 32];
  __shared__ unsigned short Bs[128 * 32];
  const int tid = threadIdx.x;
  const int wid = tid >> 6, lane = tid & 63;
  const int bn = blockIdx.x, bm = blockIdx.y;
  const int m0 = bm * 128, n0 = bn * 128;
  const int wr = wid >> 1, wc = wid & 1;
  f32x4 acc[4][4] = {};
  const int srow = tid >> 2;
  const int scol = (tid & 3) * 8;
  const unsigned short* ag = A + (size_t)(m0 + srow) * EDz + scol;
  const unsigned short* bg = Bw + (size_t)(n0 + srow) * EDz + scol;
  char* asb = (char*)As + wid * 1024;
  char* bsb = (char*)Bs + wid * 1024;
  const int arow = wr * 64 + (lane & 15);
  const int brow = wc * 64 + (lane & 15);
  const int kr = (lane >> 4) * 8;

  for (int k0 = 0; k0 < EDz; k0 += 32) {
    __builtin_amdgcn_global_load_lds(
        (const __attribute__((address_space(1))) void*)(ag + k0),
        (__attribute__((address_space(3))) void*)asb, 16, 0, 0);
    __builtin_amdgcn_global_load_lds(
        (const __attribute__((address_space(1))) void*)(ag + 64 * EDz + k0),
        (__attribute__((address_space(3))) void*)(asb + 4096), 16, 0, 0);
    __builtin_amdgcn_global_load_lds(
        (const __attribute__((address_space(1))) void*)(bg + k0),
        (__attribute__((address_space(3))) void*)bsb, 16, 0, 0);
    __builtin_amdgcn_global_load_lds(
        (const __attribute__((address_space(1))) void*)(bg + 64 * EDz + k0),
        (__attribute__((address_space(3))) void*)(bsb + 4096), 16, 0, 0);
    __syncthreads();
    bf16x8 af[4], bfr[4];
#pragma unroll
    for (int i = 0; i < 4; i++)
      af[i] = *reinterpret_cast<const bf16x8*>(&As[(arow + i * 16) * 32 + kr]);
#pragma unroll
    for (int j = 0; j < 4; j++)
      bfr[j] = *reinterpret_cast<const bf16x8*>(&Bs[(brow + j * 16) * 32 + kr]);
#pragma unroll
    for (int i = 0; i < 4; i++)
#pragma unroll
      for (int j = 0; j < 4; j++)
        acc[i][j] = __builtin_amdgcn_mfma_f32_16x16x32_bf16(af[i], bfr[j], acc[i][j], 0, 0, 0);
    __syncthreads();
  }
  const int r4 = (lane >> 4) * 4;
  const int cn = lane & 15;
#pragma unroll
  for (int j = 0; j < 4; j++) {
    const int n = n0 + wc * 64 + j * 16 + cn;
    const float bb = bias[n];
#pragma unroll
    for (int i = 0; i < 4; i++) {
      const int mb = m0 + wr * 64 + i * 16 + r4;
#pragma unroll
      for (int t = 0; t < 4; t++)
        Cm[(size_t)(mb + t) * NALL + n] = f2bf(acc[i][j][t] + bb);
    }
  }
}

// ---------------- gate + v: per-token RMSNorms, qk gate, v = gate*value ----------------
__global__ __launch_bounds__(256) void k_gate(const float* __restrict__ hidden,
                                              const unsigned short* __restrict__ kv,
                                              const float* __restrict__ k_scale,
                                              const float* __restrict__ q_scale,
                                              unsigned short* __restrict__ vbuf,
                                              float* __restrict__ rstd) {
  const int t = blockIdx.x;
  const int tid = threadIdx.x;
  const int lane = tid & 63, w = tid >> 6;
  const int c0 = tid * 8;
  __shared__ float sred[4][13];
  float val[8];
  {
    bf16x8 raw = *reinterpret_cast<const bf16x8*>(kv + (size_t)t * NALL + Gz * Cz + c0);
#pragma unroll
    for (int i = 0; i < 8; i++) val[i] = (float)raw[i];
  }
  float p[13];
#pragma unroll
  for (int j = 0; j < 13; j++) p[j] = 0.f;
#pragma unroll
  for (int i = 0; i < 8; i++) p[12] += val[i] * val[i];
#pragma unroll
  for (int g = 0; g < 4; g++) {
    const float* qp = hidden + (size_t)t * (Gz * Cz) + g * Cz + c0;
    f32x4 q0 = *reinterpret_cast<const f32x4*>(qp);
    f32x4 q1 = *reinterpret_cast<const f32x4*>(qp + 4);
    bf16x8 kr = *reinterpret_cast<const bf16x8*>(kv + (size_t)t * NALL + g * Cz + c0);
    f32x4 qs0 = *reinterpret_cast<const f32x4*>(q_scale + g * Cz + c0);
    f32x4 qs1 = *reinterpret_cast<const f32x4*>(q_scale + g * Cz + c0 + 4);
    f32x4 ks0 = *reinterpret_cast<const f32x4*>(k_scale + g * Cz + c0);
    f32x4 ks1 = *reinterpret_cast<const f32x4*>(k_scale + g * Cz + c0 + 4);
#pragma unroll
    for (int i = 0; i < 8; i++) {
      float qi = (i < 4) ? q0[i] : q1[i - 4];
      float ki = (float)kr[i];
      float qsi = (i < 4) ? qs0[i] : qs1[i - 4];
      float ksi = (i < 4) ? ks0[i] : ks1[i - 4];
      p[3 * g + 0] += qi * qi;
      p[3 * g + 1] += ki * ki;
      p[3 * g + 2] += qi * qsi * ki * ksi;
    }
  }
#pragma unroll
  for (int j = 0; j < 13; j++) {
    float x = p[j];
    for (int off = 32; off; off >>= 1) x += __shfl_down(x, off);
    if (lane == 0) sred[w][j] = x;
  }
  __syncthreads();
  float f[13];
#pragma unroll
  for (int j = 0; j < 13; j++)
    f[j] = sred[0][j] + sred[1][j] + sred[2][j] + sred[3][j];

  const float invC = 1.f / 2048.f;
  const float inv_sqrtC = 0.02209708691f;  // 1/sqrt(2048)
  const float msqv = f[12] * invC;
#pragma unroll
  for (int g = 0; g < 4; g++) {
    float rq = rsqrtf(f[3 * g + 0] * invC + 1e-6f);
    float rk = rsqrtf(f[3 * g + 1] * invC + 1e-6f);
    float qk = f[3 * g + 2] * rq * rk * inv_sqrtC;
    float l = sqrtf(fmaxf(fabsf(qk), 1e-6f));
    l = (qk < 0.f) ? -l : l;
    float gate = 1.f / (1.f + expf(-l));
    u16x8 ov;
#pragma unroll
    for (int i = 0; i < 8; i++) ov[i] = f2bf(gate * val[i]);
    *reinterpret_cast<u16x8*>(vbuf + (size_t)t * (Gz * Cz) + g * Cz + c0) = ov;
    if (tid == 0) rstd[t * 4 + g] = rsqrtf(gate * gate * msqv + 1e-5f);
  }
}

// ---------------- conv: y[s] = silu(w3*xn[s]+w2*xn[s-3]+w1*xn[s-6]+w0*xn[s-9]); out = v+y
__global__ __launch_bounds__(256) void k_conv(const unsigned short* __restrict__ vbuf,
                                              const float* __restrict__ rstd,
                                              const float* __restrict__ conv_scale,
                                              const float* __restrict__ conv_w,
                                              float* __restrict__ out) {
  const int c = blockIdx.x * 256 + threadIdx.x;       // 0..2047
  const int r = blockIdx.y % 3, seg = blockIdx.y / 3; // residue class, s-segment
  const int bg = blockIdx.z;
  const int b = bg >> 2, g = bg & 3;
  const int ch = g * Cz + c;
  const float cs = conv_scale[ch];
  const float w0 = conv_w[0 * 8192 + ch], w1 = conv_w[1 * 8192 + ch];
  const float w2 = conv_w[2 * 8192 + ch], w3 = conv_w[3 * 8192 + ch];
  const int s_begin = seg * 512, s_end = s_begin + 512;
  const int s0 = s_begin + ((r - s_begin) % 3 + 3) % 3;

  auto ldxn = [&](int s) -> float {
    if (s < 0) return 0.f;
    float v = bf2f(vbuf[(size_t)(b * Sz + s) * 8192 + ch]);
    return v * rstd[(b * Sz + s) * 4 + g] * cs;
  };
  float p1 = ldxn(s0 - 3), p2 = ldxn(s0 - 6), p3 = ldxn(s0 - 9);
  for (int s = s0; s < s_end; s += 3) {
    const size_t idx = (size_t)(b * Sz + s) * 8192 + ch;
    float v = bf2f(vbuf[idx]);
    float xn = v * rstd[(b * Sz + s) * 4 + g] * cs;
    float y = w3 * xn + w2 * p1 + w1 * p2 + w0 * p3;
    float sy = y / (1.f + expf(-y));
    out[idx] = v + sy;
    p3 = p2; p2 = p1; p1 = xn;
  }
}

extern "C" void kernel_launch(void* const* d_in, const int* in_sizes, int n_in,
                              void* d_out, int out_size, void* d_ws, size_t ws_size,
                              hipStream_t stream) {
  const float* hidden     = (const float*)d_in[0];
  const int*   hashids    = (const int*)d_in[1];
  const float* table      = (const float*)d_in[2];
  const float* key_w      = (const float*)d_in[3];
  const float* key_b      = (const float*)d_in[4];
  const float* k_scale    = (const float*)d_in[5];
  const float* q_scale    = (const float*)d_in[6];
  const float* value_w    = (const float*)d_in[7];
  const float* value_b    = (const float*)d_in[8];
  const float* conv_scale = (const float*)d_in[9];
  const float* conv_w     = (const float*)d_in[10];
  float* out = (float*)d_out;
  char* ws = (char*)d_ws;

  unsigned short* emb = (unsigned short*)(ws + 0);          //  8,388,608 B
  unsigned short* Wt  = (unsigned short*)(ws + 8388608);    // 20,971,520 B
  unsigned short* kvb = (unsigned short*)(ws + 29360128);   // 83,886,080 B
  unsigned short* vb  = (unsigned short*)(ws + 113246208);  // 67,108,864 B
  float* rstd = (float*)(ws + 180355072);                   //     65,536 B
  float* bias = (float*)(ws + 180420608);                   //     40,960 B

  k_bias<<<dim3(40), dim3(256), 0, stream>>>(key_b, value_b, bias);
  k_prepw<<<dim3(2048, 5), dim3(256), 0, stream>>>(key_w, value_w, Wt);
  k_gather<<<dim3(Tz), dim3(256), 0, stream>>>(hashids, table, emb);
  k_gemm<<<dim3(80, 32), dim3(256), 0, stream>>>(emb, Wt, bias, kvb);
  k_gate<<<dim3(Tz), dim3(256), 0, stream>>>(hidden, kvb, k_scale, q_scale, vb, rstd);
  k_conv<<<dim3(8, 12, 8), dim3(256), 0, stream>>>(vb, rstd, conv_scale, conv_w, out);
}

// Round 2
// 270.633 us; speedup vs baseline: 1.0234x; 1.0234x over previous
//
#include <hip/hip_runtime.h>
#include <cstdint>
#include <cstddef>

typedef __attribute__((ext_vector_type(8))) __bf16 bf16x8;
typedef __attribute__((ext_vector_type(4))) float f32x4;
typedef __attribute__((ext_vector_type(4))) unsigned short u16x4;
typedef __attribute__((ext_vector_type(8))) unsigned short u16x8;

static constexpr int Bz = 2, Sz = 2048, Gz = 4, Cz = 2048;
static constexpr int Hh = 16, EDz = 1024;
static constexpr int Tz = Bz * Sz;          // 4096 tokens
static constexpr int NALL = Gz * Cz + Cz;   // 10240 output cols

__constant__ int OFF16[16] = {0, 100003, 200022, 300065, 400114, 500171, 600240,
                              700343, 800452, 900581, 1000732, 1100885, 1201054,
                              1301237, 1401426, 1501619};

__device__ __forceinline__ float bf2f(unsigned short s) {
  union { unsigned u; float f; } x; x.u = ((unsigned)s) << 16; return x.f;
}
__device__ __forceinline__ unsigned short f2bf(float f) {
  union { float f; unsigned u; } x; x.f = f;
  unsigned r = x.u + 0x7fff + ((x.u >> 16) & 1);
  return (unsigned short)(r >> 16);
}

// ---------------- bias concat ----------------
__global__ __launch_bounds__(256) void k_bias(const float* __restrict__ key_b,
                                              const float* __restrict__ value_b,
                                              float* __restrict__ bias) {
  int n = blockIdx.x * 256 + threadIdx.x;
  bias[n] = (n < Gz * Cz) ? key_b[n] : value_b[n - Gz * Cz];
}

// ---------------- weight transpose + cast: Wt[n][k] bf16 ----------------
__global__ __launch_bounds__(256) void k_prepw(const float* __restrict__ key_w,
                                               const float* __restrict__ value_w,
                                               unsigned short* __restrict__ Wt) {
  __shared__ float tile[32][33];
  const int mat = blockIdx.y;
  const int ot = blockIdx.x & 63, kt = blockIdx.x >> 6;
  const float* src = (mat < 4) ? (key_w + (size_t)mat * EDz * Cz) : value_w;
  const int tx = threadIdx.x & 31, ty = threadIdx.x >> 5;
#pragma unroll
  for (int i = 0; i < 4; i++)
    tile[ty + i * 8][tx] = src[(size_t)(kt * 32 + ty + i * 8) * Cz + ot * 32 + tx];
  __syncthreads();
#pragma unroll
  for (int i = 0; i < 4; i++)
    Wt[(size_t)(mat * Cz + ot * 32 + ty + i * 8) * EDz + kt * 32 + tx] =
        f2bf(tile[tx][ty + i * 8]);
}

// ---------------- gather + cast: emb[t][1024] bf16 ----------------
__global__ __launch_bounds__(256) void k_gather(const int* __restrict__ ids,
                                                const float* __restrict__ table,
                                                unsigned short* __restrict__ emb) {
  const int t = blockIdx.x;
  const int tid = threadIdx.x;
  const int h = tid >> 4;
  const int d = (tid & 15) * 4;
  const long row = (long)(ids[t * Hh + h] + OFF16[h]);
  f32x4 v = *reinterpret_cast<const f32x4*>(table + row * 64 + d);
  u16x4 o;
#pragma unroll
  for (int i = 0; i < 4; i++) o[i] = f2bf(v[i]);
  *reinterpret_cast<u16x4*>(emb + (size_t)t * EDz + tid * 4) = o;
}

// ---------------- GEMM: kv[4096][10240] = emb @ Wt^T + bias ----------------
// 256x256 tile, BK=64, 8 waves (2M x 4N), 8-phase counted-vmcnt schedule,
// st_16x32 swizzled subtiled LDS. Raw s_barrier only (no __syncthreads drain).
#define GEMM_BAR  asm volatile("s_barrier" ::: "memory")
#define GEMM_V4   asm volatile("s_waitcnt vmcnt(4)" ::: "memory")

__global__ __launch_bounds__(512, 2) void k_gemm8(const unsigned short* __restrict__ A,
                                                  const unsigned short* __restrict__ Bw,
                                                  const float* __restrict__ bias,
                                                  unsigned short* __restrict__ Cm) {
  __shared__ unsigned short s_lds[65536];  // 128 KiB: A 64K (2 buf x 2 half x 16K), B same
  char* lds_c = (char*)s_lds;

  const int tid = threadIdx.x;
  const int wid = tid >> 6, lane = tid & 63;
  const int wr = wid >> 2, wc = wid & 3;            // 2M x 4N waves

  const int bid = blockIdx.x;
  const int swz = (bid & 7) * 80 + (bid >> 3);      // XCD swizzle, 640 = 8*80
  const int bm = swz / 40, bn = swz % 40;
  const int m0 = bm * 256, n0 = bn * 256;

  // stage decode: linear LDS pos -> (row,col) of half-tile under subtiled+swizzled map
  int rq[2], kq[2];
#pragma unroll
  for (int q = 0; q < 2; q++) {
    int x = q * 8192 + wid * 1024 + lane * 16;
    int y = x ^ (((x >> 9) & 1) << 5);
    rq[q] = ((y >> 11) & 7) * 16 + ((y >> 6) & 15);
    kq[q] = ((y >> 10) & 1) * 32 + ((y >> 1) & 31);
  }
  // per-lane read base inside a half-tile (subtiled + swizzle), const offsets added per frag
  const int rdb = (((lane & 15) << 6) + ((lane >> 4) << 4)) ^ (((lane >> 3) & 1) << 5);

  const unsigned short* Arow0 = A + (size_t)m0 * EDz;          // A half0 rows
  const unsigned short* Arow1 = A + (size_t)(m0 + 128) * EDz;  // A half1
  const unsigned short* Brow0 = Bw + (size_t)n0 * EDz;
  const unsigned short* Brow1 = Bw + (size_t)(n0 + 128) * EDz;

  auto STAGE = [&](const unsigned short* grow, int ldsOff, int kt) {
#pragma unroll
    for (int q = 0; q < 2; q++) {
      const unsigned short* src = grow + (size_t)rq[q] * EDz + kt * 64 + kq[q];
      __builtin_amdgcn_global_load_lds(
          (const __attribute__((address_space(1))) void*)src,
          (__attribute__((address_space(3))) void*)(lds_c + ldsOff + q * 8192 + wid * 1024),
          16, 0, 0);
    }
  };
  // LDS region offsets: A: buf*32768 + half*16384 ; B: 65536 + buf*32768 + half*16384

  f32x4 acc[8][4] = {};
  bf16x8 Af[4][2], Bl[2][2], Bh[2][2];

  auto RD_A = [&](int buf, int msel) {
    const char* p = lds_c + buf * 32768 + wr * 16384 + rdb;
#pragma unroll
    for (int m = 0; m < 4; m++)
#pragma unroll
      for (int ks = 0; ks < 2; ks++)
        Af[m][ks] = *reinterpret_cast<const bf16x8*>(p + (msel * 4 + m) * 2048 + ks * 1024);
  };
  auto RD_B = [&](int buf, int nsel, bf16x8 (&Bf)[2][2]) {
    const char* p = lds_c + 65536 + buf * 32768 + (wc >> 1) * 16384 + (wc & 1) * 8192 + rdb;
#pragma unroll
    for (int n = 0; n < 2; n++)
#pragma unroll
      for (int ks = 0; ks < 2; ks++)
        Bf[n][ks] = *reinterpret_cast<const bf16x8*>(p + (nsel * 2 + n) * 2048 + ks * 1024);
  };
  auto MM = [&](int msel, int nsel, bf16x8 (&Bf)[2][2]) {
    __builtin_amdgcn_s_setprio(1);
#pragma unroll
    for (int m = 0; m < 4; m++)
#pragma unroll
      for (int n = 0; n < 2; n++)
#pragma unroll
        for (int ks = 0; ks < 2; ks++)
          acc[msel * 4 + m][nsel * 2 + n] = __builtin_amdgcn_mfma_f32_16x16x32_bf16(
              Af[m][ks], Bf[n][ks], acc[msel * 4 + m][nsel * 2 + n], 0, 0, 0);
    __builtin_amdgcn_s_setprio(0);
  };

  // ---- prologue: tile0 -> buf0 (all), tile1 B-halves -> buf1 ----
  STAGE(Arow0, 0,             0);   // A0 buf0
  STAGE(Arow1, 16384,         0);   // A1 buf0
  STAGE(Brow0, 65536,         0);   // B0 buf0
  STAGE(Brow1, 65536 + 16384, 0);   // B1 buf0
  STAGE(Brow0, 65536 + 32768,         1);  // B0 buf1 tile1
  STAGE(Brow1, 65536 + 32768 + 16384, 1);  // B1 buf1 tile1
  GEMM_V4;   // drain tile0, keep tile1-B in flight
  GEMM_BAR;

  for (int i = 0; i < 8; ++i) {
    const int o  = 2 * i + 1;
    const int t2 = (2 * i + 2 > 15) ? 15 : 2 * i + 2;
    const int t3 = (2 * i + 3 > 15) ? 15 : 2 * i + 3;
    // ph1: MFMA e-g1 (m0-3 x n0-1); reads e-g1; stage A0(buf1, tile o)
    RD_A(0, 0); RD_B(0, 0, Bl);
    STAGE(Arow0, 32768, o);
    GEMM_BAR; MM(0, 0, Bl); GEMM_BAR;
    // ph2: e-g2 (m0-3 x n2-3); stage A1(buf1, o)
    RD_B(0, 1, Bh);
    STAGE(Arow1, 32768 + 16384, o);
    GEMM_BAR; MM(0, 1, Bh); GEMM_BAR;
    // ph3: e-g3 (m4-7 x n0-1); stage B0(buf0, t2)
    RD_A(0, 1);
    STAGE(Brow0, 65536, t2);
    GEMM_BAR; MM(1, 0, Bl); GEMM_BAR;
    // ph4: e-g4 (m4-7 x n2-3); stage B1(buf0, t2); GATE for buf1 reads
    STAGE(Brow1, 65536 + 16384, t2);
    GEMM_V4;
    GEMM_BAR; MM(1, 1, Bh); GEMM_BAR;
    // ph5: o-g1; stage A0(buf0, t2)
    RD_A(1, 0); RD_B(1, 0, Bl);
    STAGE(Arow0, 0, t2);
    GEMM_BAR; MM(0, 0, Bl); GEMM_BAR;
    // ph6: o-g2; stage A1(buf0, t2)
    RD_B(1, 1, Bh);
    STAGE(Arow1, 16384, t2);
    GEMM_BAR; MM(0, 1, Bh); GEMM_BAR;
    // ph7: o-g3; stage B0(buf1, t3)
    RD_A(1, 1);
    STAGE(Brow0, 65536 + 32768, t3);
    GEMM_BAR; MM(1, 0, Bl); GEMM_BAR;
    // ph8: o-g4; stage B1(buf1, t3); GATE for next-iter buf0 reads
    STAGE(Brow1, 65536 + 32768 + 16384, t3);
    GEMM_V4;
    GEMM_BAR; MM(1, 1, Bh); GEMM_BAR;
  }

  // ---- epilogue: bias + bf16 store ----
#pragma unroll
  for (int mrep = 0; mrep < 8; mrep++) {
    const int row = m0 + wr * 128 + mrep * 16 + (lane >> 4) * 4;
#pragma unroll
    for (int nrep = 0; nrep < 4; nrep++) {
      const int col = n0 + wc * 64 + nrep * 16 + (lane & 15);
      const float bb = bias[col];
#pragma unroll
      for (int t = 0; t < 4; t++)
        Cm[(size_t)(row + t) * NALL + col] = f2bf(acc[mrep][nrep][t] + bb);
    }
  }
}

// ---------------- gate + v ----------------
__global__ __launch_bounds__(256) void k_gate(const float* __restrict__ hidden,
                                              const unsigned short* __restrict__ kv,
                                              const float* __restrict__ k_scale,
                                              const float* __restrict__ q_scale,
                                              unsigned short* __restrict__ vbuf,
                                              float* __restrict__ rstd) {
  const int t = blockIdx.x;
  const int tid = threadIdx.x;
  const int lane = tid & 63, w = tid >> 6;
  const int c0 = tid * 8;
  __shared__ float sred[4][13];
  float val[8];
  {
    bf16x8 raw = *reinterpret_cast<const bf16x8*>(kv + (size_t)t * NALL + Gz * Cz + c0);
#pragma unroll
    for (int i = 0; i < 8; i++) val[i] = (float)raw[i];
  }
  float p[13];
#pragma unroll
  for (int j = 0; j < 13; j++) p[j] = 0.f;
#pragma unroll
  for (int i = 0; i < 8; i++) p[12] += val[i] * val[i];
#pragma unroll
  for (int g = 0; g < 4; g++) {
    const float* qp = hidden + (size_t)t * (Gz * Cz) + g * Cz + c0;
    f32x4 q0 = *reinterpret_cast<const f32x4*>(qp);
    f32x4 q1 = *reinterpret_cast<const f32x4*>(qp + 4);
    bf16x8 kr = *reinterpret_cast<const bf16x8*>(kv + (size_t)t * NALL + g * Cz + c0);
    f32x4 qs0 = *reinterpret_cast<const f32x4*>(q_scale + g * Cz + c0);
    f32x4 qs1 = *reinterpret_cast<const f32x4*>(q_scale + g * Cz + c0 + 4);
    f32x4 ks0 = *reinterpret_cast<const f32x4*>(k_scale + g * Cz + c0);
    f32x4 ks1 = *reinterpret_cast<const f32x4*>(k_scale + g * Cz + c0 + 4);
#pragma unroll
    for (int i = 0; i < 8; i++) {
      float qi = (i < 4) ? q0[i] : q1[i - 4];
      float ki = (float)kr[i];
      float qsi = (i < 4) ? qs0[i] : qs1[i - 4];
      float ksi = (i < 4) ? ks0[i] : ks1[i - 4];
      p[3 * g + 0] += qi * qi;
      p[3 * g + 1] += ki * ki;
      p[3 * g + 2] += qi * qsi * ki * ksi;
    }
  }
#pragma unroll
  for (int j = 0; j < 13; j++) {
    float x = p[j];
    for (int off = 32; off; off >>= 1) x += __shfl_down(x, off);
    if (lane == 0) sred[w][j] = x;
  }
  __syncthreads();
  float f[13];
#pragma unroll
  for (int j = 0; j < 13; j++)
    f[j] = sred[0][j] + sred[1][j] + sred[2][j] + sred[3][j];

  const float invC = 1.f / 2048.f;
  const float inv_sqrtC = 0.02209708691f;
  const float msqv = f[12] * invC;
#pragma unroll
  for (int g = 0; g < 4; g++) {
    float rq = rsqrtf(f[3 * g + 0] * invC + 1e-6f);
    float rk = rsqrtf(f[3 * g + 1] * invC + 1e-6f);
    float qk = f[3 * g + 2] * rq * rk * inv_sqrtC;
    float l = sqrtf(fmaxf(fabsf(qk), 1e-6f));
    l = (qk < 0.f) ? -l : l;
    float gate = 1.f / (1.f + expf(-l));
    u16x8 ov;
#pragma unroll
    for (int i = 0; i < 8; i++) ov[i] = f2bf(gate * val[i]);
    *reinterpret_cast<u16x8*>(vbuf + (size_t)t * (Gz * Cz) + g * Cz + c0) = ov;
    if (tid == 0) rstd[t * 4 + g] = rsqrtf(gate * gate * msqv + 1e-5f);
  }
}

// ---------------- conv ----------------
__global__ __launch_bounds__(256) void k_conv(const unsigned short* __restrict__ vbuf,
                                              const float* __restrict__ rstd,
                                              const float* __restrict__ conv_scale,
                                              const float* __restrict__ conv_w,
                                              float* __restrict__ out) {
  const int c = blockIdx.x * 256 + threadIdx.x;
  const int r = blockIdx.y % 3, seg = blockIdx.y / 3;
  const int bg = blockIdx.z;
  const int b = bg >> 2, g = bg & 3;
  const int ch = g * Cz + c;
  const float cs = conv_scale[ch];
  const float w0 = conv_w[0 * 8192 + ch], w1 = conv_w[1 * 8192 + ch];
  const float w2 = conv_w[2 * 8192 + ch], w3 = conv_w[3 * 8192 + ch];
  const int s_begin = seg * 512, s_end = s_begin + 512;
  const int s0 = s_begin + ((r - s_begin) % 3 + 3) % 3;

  auto ldxn = [&](int s) -> float {
    if (s < 0) return 0.f;
    float v = bf2f(vbuf[(size_t)(b * Sz + s) * 8192 + ch]);
    return v * rstd[(b * Sz + s) * 4 + g] * cs;
  };
  float p1 = ldxn(s0 - 3), p2 = ldxn(s0 - 6), p3 = ldxn(s0 - 9);
  for (int s = s0; s < s_end; s += 3) {
    const size_t idx = (size_t)(b * Sz + s) * 8192 + ch;
    float v = bf2f(vbuf[idx]);
    float xn = v * rstd[(b * Sz + s) * 4 + g] * cs;
    float y = w3 * xn + w2 * p1 + w1 * p2 + w0 * p3;
    float sy = y / (1.f + expf(-y));
    out[idx] = v + sy;
    p3 = p2; p2 = p1; p1 = xn;
  }
}

extern "C" void kernel_launch(void* const* d_in, const int* in_sizes, int n_in,
                              void* d_out, int out_size, void* d_ws, size_t ws_size,
                              hipStream_t stream) {
  const float* hidden     = (const float*)d_in[0];
  const int*   hashids    = (const int*)d_in[1];
  const float* table      = (const float*)d_in[2];
  const float* key_w      = (const float*)d_in[3];
  const float* key_b      = (const float*)d_in[4];
  const float* k_scale    = (const float*)d_in[5];
  const float* q_scale    = (const float*)d_in[6];
  const float* value_w    = (const float*)d_in[7];
  const float* value_b    = (const float*)d_in[8];
  const float* conv_scale = (const float*)d_in[9];
  const float* conv_w     = (const float*)d_in[10];
  float* out = (float*)d_out;
  char* ws = (char*)d_ws;

  unsigned short* emb = (unsigned short*)(ws + 0);          //  8,388,608 B
  unsigned short* Wt  = (unsigned short*)(ws + 8388608);    // 20,971,520 B
  unsigned short* kvb = (unsigned short*)(ws + 29360128);   // 83,886,080 B
  unsigned short* vb  = (unsigned short*)(ws + 113246208);  // 67,108,864 B
  float* rstd = (float*)(ws + 180355072);                   //     65,536 B
  float* bias = (float*)(ws + 180420608);                   //     40,960 B

  k_bias<<<dim3(40), dim3(256), 0, stream>>>(key_b, value_b, bias);
  k_prepw<<<dim3(2048, 5), dim3(256), 0, stream>>>(key_w, value_w, Wt);
  k_gather<<<dim3(Tz), dim3(256), 0, stream>>>(hashids, table, emb);
  k_gemm8<<<dim3(640), dim3(512), 0, stream>>>(emb, Wt, bias, kvb);
  k_gate<<<dim3(Tz), dim3(256), 0, stream>>>(hidden, kvb, k_scale, q_scale, vb, rstd);
  k_conv<<<dim3(8, 12, 8), dim3(256), 0, stream>>>(vb, rstd, conv_scale, conv_w, out);
}

// Round 3
// 224.000 us; speedup vs baseline: 1.2364x; 1.2082x over previous
//
#include <hip/hip_runtime.h>
#include <cstdint>
#include <cstddef>

typedef __attribute__((ext_vector_type(8))) __bf16 bf16x8;
typedef __attribute__((ext_vector_type(4))) float f32x4;
typedef __attribute__((ext_vector_type(4))) unsigned short u16x4;
typedef __attribute__((ext_vector_type(8))) unsigned short u16x8;

static constexpr int Bz = 2, Sz = 2048, Gz = 4, Cz = 2048;
static constexpr int Hh = 16, EDz = 1024;
static constexpr int Tz = Bz * Sz;          // 4096 tokens
static constexpr int NALL = Gz * Cz + Cz;   // 10240 output cols

__constant__ int OFF16[16] = {0, 100003, 200022, 300065, 400114, 500171, 600240,
                              700343, 800452, 900581, 1000732, 1100885, 1201054,
                              1301237, 1401426, 1501619};

__device__ __forceinline__ float bf2f(unsigned short s) {
  union { unsigned u; float f; } x; x.u = ((unsigned)s) << 16; return x.f;
}
__device__ __forceinline__ unsigned short f2bf(float f) {
  union { float f; unsigned u; } x; x.f = f;
  unsigned r = x.u + 0x7fff + ((x.u >> 16) & 1);
  return (unsigned short)(r >> 16);
}

// ---------------- bias concat ----------------
__global__ __launch_bounds__(256) void k_bias(const float* __restrict__ key_b,
                                              const float* __restrict__ value_b,
                                              float* __restrict__ bias) {
  int n = blockIdx.x * 256 + threadIdx.x;
  bias[n] = (n < Gz * Cz) ? key_b[n] : value_b[n - Gz * Cz];
}

// ---------------- weight transpose + cast: Wt[n][k] bf16 ----------------
__global__ __launch_bounds__(256) void k_prepw(const float* __restrict__ key_w,
                                               const float* __restrict__ value_w,
                                               unsigned short* __restrict__ Wt) {
  __shared__ float tile[32][33];
  const int mat = blockIdx.y;
  const int ot = blockIdx.x & 63, kt = blockIdx.x >> 6;
  const float* src = (mat < 4) ? (key_w + (size_t)mat * EDz * Cz) : value_w;
  const int tx = threadIdx.x & 31, ty = threadIdx.x >> 5;
#pragma unroll
  for (int i = 0; i < 4; i++)
    tile[ty + i * 8][tx] = src[(size_t)(kt * 32 + ty + i * 8) * Cz + ot * 32 + tx];
  __syncthreads();
#pragma unroll
  for (int i = 0; i < 4; i++)
    Wt[(size_t)(mat * Cz + ot * 32 + ty + i * 8) * EDz + kt * 32 + tx] =
        f2bf(tile[tx][ty + i * 8]);
}

// ---------------- gather + cast: emb[t][1024] bf16 ----------------
__global__ __launch_bounds__(256) void k_gather(const int* __restrict__ ids,
                                                const float* __restrict__ table,
                                                unsigned short* __restrict__ emb) {
  const int t = blockIdx.x;
  const int tid = threadIdx.x;
  const int h = tid >> 4;
  const int d = (tid & 15) * 4;
  const long row = (long)(ids[t * Hh + h] + OFF16[h]);
  f32x4 v = *reinterpret_cast<const f32x4*>(table + row * 64 + d);
  u16x4 o;
#pragma unroll
  for (int i = 0; i < 4; i++) o[i] = f2bf(v[i]);
  *reinterpret_cast<u16x4*>(emb + (size_t)t * EDz + tid * 4) = o;
}

// ---------------- GEMM: kv[4096][10240] = emb @ Wt^T + bias ----------------
// 256x256 tile, BK=64, 8 waves (2M x 4N), 8-phase counted-vmcnt schedule,
// st_16x32 swizzled subtiled LDS. Raw s_barrier only (no __syncthreads drain).
#define GEMM_BAR  asm volatile("s_barrier" ::: "memory")
#define GEMM_V4   asm volatile("s_waitcnt vmcnt(4)" ::: "memory")

__global__ __launch_bounds__(512, 2) void k_gemm8(const unsigned short* __restrict__ A,
                                                  const unsigned short* __restrict__ Bw,
                                                  const float* __restrict__ bias,
                                                  unsigned short* __restrict__ Cm) {
  __shared__ unsigned short s_lds[65536];  // 128 KiB
  char* lds_c = (char*)s_lds;

  const int tid = threadIdx.x;
  const int wid = tid >> 6, lane = tid & 63;
  const int wr = wid >> 2, wc = wid & 3;

  const int bid = blockIdx.x;
  const int swz = (bid & 7) * 80 + (bid >> 3);
  const int bm = swz / 40, bn = swz % 40;
  const int m0 = bm * 256, n0 = bn * 256;

  int rq[2], kq[2];
#pragma unroll
  for (int q = 0; q < 2; q++) {
    int x = q * 8192 + wid * 1024 + lane * 16;
    int y = x ^ (((x >> 9) & 1) << 5);
    rq[q] = ((y >> 11) & 7) * 16 + ((y >> 6) & 15);
    kq[q] = ((y >> 10) & 1) * 32 + ((y >> 1) & 31);
  }
  const int rdb = (((lane & 15) << 6) + ((lane >> 4) << 4)) ^ (((lane >> 3) & 1) << 5);

  const unsigned short* Arow0 = A + (size_t)m0 * EDz;
  const unsigned short* Arow1 = A + (size_t)(m0 + 128) * EDz;
  const unsigned short* Brow0 = Bw + (size_t)n0 * EDz;
  const unsigned short* Brow1 = Bw + (size_t)(n0 + 128) * EDz;

  auto STAGE = [&](const unsigned short* grow, int ldsOff, int kt) {
#pragma unroll
    for (int q = 0; q < 2; q++) {
      const unsigned short* src = grow + (size_t)rq[q] * EDz + kt * 64 + kq[q];
      __builtin_amdgcn_global_load_lds(
          (const __attribute__((address_space(1))) void*)src,
          (__attribute__((address_space(3))) void*)(lds_c + ldsOff + q * 8192 + wid * 1024),
          16, 0, 0);
    }
  };

  f32x4 acc[8][4] = {};
  bf16x8 Af[4][2], Bl[2][2], Bh[2][2];

  auto RD_A = [&](int buf, int msel) {
    const char* p = lds_c + buf * 32768 + wr * 16384 + rdb;
#pragma unroll
    for (int m = 0; m < 4; m++)
#pragma unroll
      for (int ks = 0; ks < 2; ks++)
        Af[m][ks] = *reinterpret_cast<const bf16x8*>(p + (msel * 4 + m) * 2048 + ks * 1024);
  };
  auto RD_B = [&](int buf, int nsel, bf16x8 (&Bf)[2][2]) {
    const char* p = lds_c + 65536 + buf * 32768 + (wc >> 1) * 16384 + (wc & 1) * 8192 + rdb;
#pragma unroll
    for (int n = 0; n < 2; n++)
#pragma unroll
      for (int ks = 0; ks < 2; ks++)
        Bf[n][ks] = *reinterpret_cast<const bf16x8*>(p + (nsel * 2 + n) * 2048 + ks * 1024);
  };
  auto MM = [&](int msel, int nsel, bf16x8 (&Bf)[2][2]) {
    __builtin_amdgcn_s_setprio(1);
#pragma unroll
    for (int m = 0; m < 4; m++)
#pragma unroll
      for (int n = 0; n < 2; n++)
#pragma unroll
        for (int ks = 0; ks < 2; ks++)
          acc[msel * 4 + m][nsel * 2 + n] = __builtin_amdgcn_mfma_f32_16x16x32_bf16(
              Af[m][ks], Bf[n][ks], acc[msel * 4 + m][nsel * 2 + n], 0, 0, 0);
    __builtin_amdgcn_s_setprio(0);
  };

  STAGE(Arow0, 0,             0);
  STAGE(Arow1, 16384,         0);
  STAGE(Brow0, 65536,         0);
  STAGE(Brow1, 65536 + 16384, 0);
  STAGE(Brow0, 65536 + 32768,         1);
  STAGE(Brow1, 65536 + 32768 + 16384, 1);
  GEMM_V4;
  GEMM_BAR;

  for (int i = 0; i < 8; ++i) {
    const int o  = 2 * i + 1;
    const int t2 = (2 * i + 2 > 15) ? 15 : 2 * i + 2;
    const int t3 = (2 * i + 3 > 15) ? 15 : 2 * i + 3;
    RD_A(0, 0); RD_B(0, 0, Bl);
    STAGE(Arow0, 32768, o);
    GEMM_BAR; MM(0, 0, Bl); GEMM_BAR;
    RD_B(0, 1, Bh);
    STAGE(Arow1, 32768 + 16384, o);
    GEMM_BAR; MM(0, 1, Bh); GEMM_BAR;
    RD_A(0, 1);
    STAGE(Brow0, 65536, t2);
    GEMM_BAR; MM(1, 0, Bl); GEMM_BAR;
    STAGE(Brow1, 65536 + 16384, t2);
    GEMM_V4;
    GEMM_BAR; MM(1, 1, Bh); GEMM_BAR;
    RD_A(1, 0); RD_B(1, 0, Bl);
    STAGE(Arow0, 0, t2);
    GEMM_BAR; MM(0, 0, Bl); GEMM_BAR;
    RD_B(1, 1, Bh);
    STAGE(Arow1, 16384, t2);
    GEMM_BAR; MM(0, 1, Bh); GEMM_BAR;
    RD_A(1, 1);
    STAGE(Brow0, 65536 + 32768, t3);
    GEMM_BAR; MM(1, 0, Bl); GEMM_BAR;
    STAGE(Brow1, 65536 + 32768 + 16384, t3);
    GEMM_V4;
    GEMM_BAR; MM(1, 1, Bh); GEMM_BAR;
  }

#pragma unroll
  for (int mrep = 0; mrep < 8; mrep++) {
    const int row = m0 + wr * 128 + mrep * 16 + (lane >> 4) * 4;
#pragma unroll
    for (int nrep = 0; nrep < 4; nrep++) {
      const int col = n0 + wc * 64 + nrep * 16 + (lane & 15);
      const float bb = bias[col];
#pragma unroll
      for (int t = 0; t < 4; t++)
        Cm[(size_t)(row + t) * NALL + col] = f2bf(acc[mrep][nrep][t] + bb);
    }
  }
}

// ---------------- gate: per-token RMSNorms + qk gate; writes gates+rstd only ----
__global__ __launch_bounds__(256) void k_gate(const float* __restrict__ hidden,
                                              const unsigned short* __restrict__ kv,
                                              const float* __restrict__ k_scale,
                                              const float* __restrict__ q_scale,
                                              float* __restrict__ gates,
                                              float* __restrict__ rstd) {
  const int t = blockIdx.x;
  const int tid = threadIdx.x;
  const int lane = tid & 63, w = tid >> 6;
  const int c0 = tid * 8;
  __shared__ float sred[4][13];
  float val[8];
  {
    bf16x8 raw = *reinterpret_cast<const bf16x8*>(kv + (size_t)t * NALL + Gz * Cz + c0);
#pragma unroll
    for (int i = 0; i < 8; i++) val[i] = (float)raw[i];
  }
  float p[13];
#pragma unroll
  for (int j = 0; j < 13; j++) p[j] = 0.f;
#pragma unroll
  for (int i = 0; i < 8; i++) p[12] += val[i] * val[i];
#pragma unroll
  for (int g = 0; g < 4; g++) {
    const float* qp = hidden + (size_t)t * (Gz * Cz) + g * Cz + c0;
    f32x4 q0 = *reinterpret_cast<const f32x4*>(qp);
    f32x4 q1 = *reinterpret_cast<const f32x4*>(qp + 4);
    bf16x8 kr = *reinterpret_cast<const bf16x8*>(kv + (size_t)t * NALL + g * Cz + c0);
    f32x4 qs0 = *reinterpret_cast<const f32x4*>(q_scale + g * Cz + c0);
    f32x4 qs1 = *reinterpret_cast<const f32x4*>(q_scale + g * Cz + c0 + 4);
    f32x4 ks0 = *reinterpret_cast<const f32x4*>(k_scale + g * Cz + c0);
    f32x4 ks1 = *reinterpret_cast<const f32x4*>(k_scale + g * Cz + c0 + 4);
#pragma unroll
    for (int i = 0; i < 8; i++) {
      float qi = (i < 4) ? q0[i] : q1[i - 4];
      float ki = (float)kr[i];
      float qsi = (i < 4) ? qs0[i] : qs1[i - 4];
      float ksi = (i < 4) ? ks0[i] : ks1[i - 4];
      p[3 * g + 0] += qi * qi;
      p[3 * g + 1] += ki * ki;
      p[3 * g + 2] += qi * qsi * ki * ksi;
    }
  }
#pragma unroll
  for (int j = 0; j < 13; j++) {
    float x = p[j];
    for (int off = 32; off; off >>= 1) x += __shfl_down(x, off);
    if (lane == 0) sred[w][j] = x;
  }
  __syncthreads();
  if (tid != 0) return;
  float f[13];
#pragma unroll
  for (int j = 0; j < 13; j++)
    f[j] = sred[0][j] + sred[1][j] + sred[2][j] + sred[3][j];

  const float invC = 1.f / 2048.f;
  const float inv_sqrtC = 0.02209708691f;
  const float msqv = f[12] * invC;
#pragma unroll
  for (int g = 0; g < 4; g++) {
    float rq = rsqrtf(f[3 * g + 0] * invC + 1e-6f);
    float rk = rsqrtf(f[3 * g + 1] * invC + 1e-6f);
    float qk = f[3 * g + 2] * rq * rk * inv_sqrtC;
    float l = sqrtf(fmaxf(fabsf(qk), 1e-6f));
    l = (qk < 0.f) ? -l : l;
    float gate = 1.f / (1.f + expf(-l));
    gates[t * 4 + g] = gate;
    rstd[t * 4 + g] = rsqrtf(gate * gate * msqv + 1e-5f);
  }
}

// ---------------- conv: v = gate*value reconstructed; vectorized u16x8/f32x4 ----
// y[s] = silu(w3*xn[s]+w2*xn[s-3]+w1*xn[s-6]+w0*xn[s-9]); out = v + y
__global__ __launch_bounds__(256) void k_conv(const unsigned short* __restrict__ kvb,
                                              const float* __restrict__ gates,
                                              const float* __restrict__ rstd,
                                              const float* __restrict__ conv_scale,
                                              const float* __restrict__ conv_w,
                                              float* __restrict__ out) {
  const int th = threadIdx.x;             // 0..255, 8 channels each
  const int r = blockIdx.x % 3, seg = blockIdx.x / 3;   // 3 residues x 32 segs
  const int bg = blockIdx.y;
  const int b = bg >> 2, g = bg & 3;
  const int c8 = th * 8;
  const int ch = g * Cz + c8;

  float cs[8], w0[8], w1[8], w2[8], w3[8];
#pragma unroll
  for (int q = 0; q < 2; q++) {
    f32x4 a = *reinterpret_cast<const f32x4*>(conv_scale + ch + q * 4);
    f32x4 t0 = *reinterpret_cast<const f32x4*>(conv_w + 0 * 8192 + ch + q * 4);
    f32x4 t1 = *reinterpret_cast<const f32x4*>(conv_w + 1 * 8192 + ch + q * 4);
    f32x4 t2 = *reinterpret_cast<const f32x4*>(conv_w + 2 * 8192 + ch + q * 4);
    f32x4 t3 = *reinterpret_cast<const f32x4*>(conv_w + 3 * 8192 + ch + q * 4);
#pragma unroll
    for (int i = 0; i < 4; i++) {
      cs[q * 4 + i] = a[i];
      w0[q * 4 + i] = t0[i]; w1[q * 4 + i] = t1[i];
      w2[q * 4 + i] = t2[i]; w3[q * 4 + i] = t3[i];
    }
  }

  const int s_begin = seg * 64, s_end = s_begin + 64;
  const int s0 = s_begin + ((r - s_begin) % 3 + 3) % 3;

  float p1[8], p2[8], p3[8];
  auto ldxn = [&](int s, float* dst) {
    if (s < 0) {
#pragma unroll
      for (int i = 0; i < 8; i++) dst[i] = 0.f;
      return;
    }
    const int t = b * Sz + s;
    const float grs = gates[t * 4 + g] * rstd[t * 4 + g];
    u16x8 raw = *reinterpret_cast<const u16x8*>(kvb + (size_t)t * NALL + Gz * Cz + c8);
#pragma unroll
    for (int i = 0; i < 8; i++) dst[i] = bf2f(raw[i]) * grs * cs[i];
  };
  ldxn(s0 - 3, p1); ldxn(s0 - 6, p2); ldxn(s0 - 9, p3);

  for (int s = s0; s < s_end; s += 3) {
    const int t = b * Sz + s;
    const float gate = gates[t * 4 + g];
    const float rsc = rstd[t * 4 + g];
    u16x8 raw = *reinterpret_cast<const u16x8*>(kvb + (size_t)t * NALL + Gz * Cz + c8);
    f32x4 o0, o1;
#pragma unroll
    for (int i = 0; i < 8; i++) {
      float v = bf2f(raw[i]) * gate;
      float xn = v * rsc * cs[i];
      float y = w3[i] * xn + w2[i] * p1[i] + w1[i] * p2[i] + w0[i] * p3[i];
      float sy = y / (1.f + expf(-y));
      float ov = v + sy;
      if (i < 4) o0[i] = ov; else o1[i - 4] = ov;
      p3[i] = p2[i]; p2[i] = p1[i]; p1[i] = xn;
    }
    float* op = out + (size_t)t * (Gz * Cz) + ch;
    *reinterpret_cast<f32x4*>(op) = o0;
    *reinterpret_cast<f32x4*>(op + 4) = o1;
  }
}

extern "C" void kernel_launch(void* const* d_in, const int* in_sizes, int n_in,
                              void* d_out, int out_size, void* d_ws, size_t ws_size,
                              hipStream_t stream) {
  const float* hidden     = (const float*)d_in[0];
  const int*   hashids    = (const int*)d_in[1];
  const float* table      = (const float*)d_in[2];
  const float* key_w      = (const float*)d_in[3];
  const float* key_b      = (const float*)d_in[4];
  const float* k_scale    = (const float*)d_in[5];
  const float* q_scale    = (const float*)d_in[6];
  const float* value_w    = (const float*)d_in[7];
  const float* value_b    = (const float*)d_in[8];
  const float* conv_scale = (const float*)d_in[9];
  const float* conv_w     = (const float*)d_in[10];
  float* out = (float*)d_out;
  char* ws = (char*)d_ws;

  unsigned short* emb = (unsigned short*)(ws + 0);          //  8,388,608 B
  unsigned short* Wt  = (unsigned short*)(ws + 8388608);    // 20,971,520 B
  unsigned short* kvb = (unsigned short*)(ws + 29360128);   // 83,886,080 B
  float* gates = (float*)(ws + 113246208);                  //     65,536 B
  float* rstd  = (float*)(ws + 113311744);                  //     65,536 B
  float* bias  = (float*)(ws + 113377280);                  //     40,960 B

  k_bias<<<dim3(40), dim3(256), 0, stream>>>(key_b, value_b, bias);
  k_prepw<<<dim3(2048, 5), dim3(256), 0, stream>>>(key_w, value_w, Wt);
  k_gather<<<dim3(Tz), dim3(256), 0, stream>>>(hashids, table, emb);
  k_gemm8<<<dim3(640), dim3(512), 0, stream>>>(emb, Wt, bias, kvb);
  k_gate<<<dim3(Tz), dim3(256), 0, stream>>>(hidden, kvb, k_scale, q_scale, gates, rstd);
  k_conv<<<dim3(96, 8), dim3(256), 0, stream>>>(kvb, gates, rstd, conv_scale, conv_w, out);
}